// Round 1
// baseline (2770.038 us; speedup 1.0000x reference)
//
#include <hip/hip_runtime.h>

typedef int v4i __attribute__((ext_vector_type(4)));

// ws layout (bytes)
#define WMAX_OFF   0
#define CNT_OFF    4
#define IMEM_OFF   64        // float[500*64]
#define BITS_OFF   131072    // ull[2*64*64]  (self-validating {bits32, tag} packets)
#define WFRAG_OFF  196608    // v4i[8192*64]  (quantized i8 hi/lo W fragments)

__global__ void sr_prep(const float* __restrict__ x, const float* __restrict__ w_in,
                        float* __restrict__ imem, unsigned* wmax_bits, unsigned* cnt) {
  int b = threadIdx.x;
  if (b == 64) *wmax_bits = 0u;
  if (b == 65) *cnt = 0u;
  if (b < 64) {
    float wi = w_in[0];
    float im = 0.0f;
    for (int t = 0; t < 500; ++t) {
      im = 0.8f * im + x[b * 500 + t] * wi;   // input LIF (Vmem mode, no reset)
      imem[t * 64 + b] = im;
    }
  }
}

__global__ void sr_wmax(const float* __restrict__ W, unsigned* wmax_bits) {
  __shared__ unsigned sm;
  if (threadIdx.x == 0) sm = 0u;
  __syncthreads();
  float m = 0.0f;
  for (size_t i = (size_t)blockIdx.x * 256 + threadIdx.x; i < 4194304ull; i += 262144ull)
    m = fmaxf(m, fabsf(W[i]));
  atomicMax(&sm, __float_as_uint(m));   // floats >=0: uint order == float order
  __syncthreads();
  if (threadIdx.x == 0) atomicMax(wmax_bits, sm);
}

// Quantize W to 16-bit fixed point, split into hi/lo i8 planes, laid out directly as
// MFMA B-fragments with a custom k-slot permutation:
//   k-slot (q, j=4d+i)  <->  source neuron m = (K*2 + (q&1))*32 + (q>>1)*4 + d + 8*i
// chosen so the consumer can expand spike bits with (word >> (sh+d)) & 0x01010101.
__global__ void sr_wquant(const float* __restrict__ W, const unsigned* __restrict__ wmax_bits,
                          v4i* __restrict__ wfr) {
  int tid = blockIdx.x * 256 + threadIdx.x;   // < 524288 = 8192 frags * 64 lanes
  int lane = tid & 63;
  int f = tid >> 6;
  int sp = f & 1;
  int nt = (f >> 1) & 1;
  int kl = (f >> 2) & 3;
  int w  = (f >> 4) & 7;
  int p  = f >> 7;
  int col = lane & 15, q = lane >> 4;
  int n = p * 32 + nt * 16 + col;
  int K = w * 4 + kl;
  float S = 32000.0f / __uint_as_float(*wmax_bits);
  int dw[4] = {0, 0, 0, 0};
  for (int j = 0; j < 16; ++j) {
    int d = j >> 2, i = j & 3;
    int m = (K * 2 + (q & 1)) * 32 + (q >> 1) * 4 + d + 8 * i;
    float wv = W[(size_t)n * 2048 + m];
    int qv = (int)rintf(wv * S);        // |qv| <= 32000
    int hi = (qv + 128) >> 8;           // hi in [-125,126]
    int lo = qv - (hi << 8);            // lo in [-128,127], qv == hi*256+lo exactly
    int v = sp ? lo : hi;
    dw[d] |= (v & 255) << (8 * i);
  }
  v4i o; o[0] = dw[0]; o[1] = dw[1]; o[2] = dw[2]; o[3] = dw[3];
  wfr[tid] = o;
}

// Persistent dataflow kernel: 64 blocks (one per 32-neuron slice), 512 threads (8 waves).
// Wave w = K-slice [256w, 256w+256); per step: 16 spike-packet loads, 16 A expansions,
// 64 i8 MFMAs (4 bt x 2 nt x 2 planes x 4 ksteps), exact int32 LDS reduce, fp32 epilogue.
__global__ __launch_bounds__(512, 2)
void sr_main(const float* __restrict__ imem, const v4i* __restrict__ wfr,
             unsigned long long* bits, const float* __restrict__ w_res,
             const unsigned* __restrict__ wmax_bits, unsigned* cnt_g,
             float* __restrict__ out) {
  extern __shared__ char smem_raw[];
  v4i* red = (v4i*)smem_raw;      // [tile g4(8)][wave(8)][lane(64)] = 64KB
  int* outl = (int*)smem_raw;     // aliased after barrier: [2048] int

  const int p = blockIdx.x;
  const int tid = threadIdx.x;
  const int w = tid >> 6;
  const int lane = tid & 63;
  const int q = lane >> 4;
  const int col = lane & 15;

  // resident W fragments: 16 x int4 = 64 VGPRs
  v4i wf[4][2][2];
  #pragma unroll
  for (int kl = 0; kl < 4; ++kl)
    #pragma unroll
    for (int nt = 0; nt < 2; ++nt)
      #pragma unroll
      for (int sp = 0; sp < 2; ++sp)
        wf[kl][nt][sp] = wfr[(size_t)(((((p * 8 + w) * 4 + kl) * 2 + nt) * 2 + sp)) * 64 + lane];

  // epilogue ownership: lane -> batch be, neurons [32p + nl0, +4)
  const int be = tid >> 3;
  const int nl0 = (tid & 7) * 4;
  const float wr0 = w_res[p * 32 + nl0 + 0];
  const float wr1 = w_res[p * 32 + nl0 + 1];
  const float wr2 = w_res[p * 32 + nl0 + 2];
  const float wr3 = w_res[p * 32 + nl0 + 3];
  float mem0 = 0, mem1 = 0, mem2 = 0, mem3 = 0;
  float sp0 = 0, sp1 = 0, sp2 = 0, sp3 = 0;
  int cnt = 0;
  const float invS = __uint_as_float(*wmax_bits) / 32000.0f;
  const unsigned sh = (unsigned)(((lane >> 5) & 1) * 4);
  const v4i vzero = {0, 0, 0, 0};

  for (int t = 0; t < 500; ++t) {
    float rec0 = 0, rec1 = 0, rec2 = 0, rec3 = 0;
    if (t > 0) {
      const size_t slotb = (size_t)((t - 1) & 1) * 4096;
      unsigned long long qw[16];
      unsigned long long stale;
      int guard = 0;
      do {  // self-validating packets: {bits32, tag=t}; retry until all 16 current
        #pragma unroll
        for (int f = 0; f < 16; ++f) {
          int bt = f >> 2, kl = f & 3;
          int K = w * 4 + kl;
          int pp = K * 2 + (q & 1);
          int bb = bt * 16 + col;
          qw[f] = __hip_atomic_load(&bits[slotb + (size_t)pp * 64 + bb],
                                    __ATOMIC_RELAXED, __HIP_MEMORY_SCOPE_AGENT);
        }
        unsigned bad = 0;
        #pragma unroll
        for (int f = 0; f < 16; ++f) bad |= (unsigned)(qw[f] >> 32) ^ (unsigned)t;
        stale = __ballot(bad != 0);
        if (stale) { __builtin_amdgcn_s_sleep(2); if (++guard > (1 << 20)) break; }
      } while (stale);

      v4i acc[4][2][2];
      #pragma unroll
      for (int bt = 0; bt < 4; ++bt)
        #pragma unroll
        for (int nt = 0; nt < 2; ++nt)
          #pragma unroll
          for (int sp = 0; sp < 2; ++sp) acc[bt][nt][sp] = vzero;

      #pragma unroll
      for (int f = 0; f < 16; ++f) {
        int bt = f >> 2, kl = f & 3;
        unsigned wb = (unsigned)qw[f];
        v4i a;  // bits -> i8 {0,1}: 2 VALU per 4 elements
        a[0] = (int)((wb >> (sh + 0)) & 0x01010101u);
        a[1] = (int)((wb >> (sh + 1)) & 0x01010101u);
        a[2] = (int)((wb >> (sh + 2)) & 0x01010101u);
        a[3] = (int)((wb >> (sh + 3)) & 0x01010101u);
        #pragma unroll
        for (int nt = 0; nt < 2; ++nt)
          #pragma unroll
          for (int sp = 0; sp < 2; ++sp)
            acc[bt][nt][sp] =
                __builtin_amdgcn_mfma_i32_16x16x64_i8(a, wf[kl][nt][sp], acc[bt][nt][sp], 0, 0, 0);
      }

      // combine planes exactly (rec_q = 256*hi + lo), cross-wave K reduction via LDS
      #pragma unroll
      for (int bt = 0; bt < 4; ++bt)
        #pragma unroll
        for (int nt = 0; nt < 2; ++nt) {
          int g4 = bt * 2 + nt;
          v4i c = acc[bt][nt][0] * 256 + acc[bt][nt][1];
          red[(g4 * 8 + w) * 64 + lane] = c;
        }
      __syncthreads();
      {
        int g4 = tid & 7, lp = tid >> 3;
        v4i s = vzero;
        #pragma unroll
        for (int ww = 0; ww < 8; ++ww) s += red[(g4 * 8 + ww) * 64 + lp];
        __syncthreads();  // red consumed; safe to alias as outl
        int bt = g4 >> 1, nt = g4 & 1;
        int ob = (bt * 16 + (lp >> 4) * 4) * 32 + nt * 16 + (lp & 15);  // C/D: col=lane&15, row=quad*4+reg
        outl[ob] = s[0];
        outl[ob + 32] = s[1];
        outl[ob + 64] = s[2];
        outl[ob + 96] = s[3];
      }
      __syncthreads();
      v4i rv = *(const v4i*)(outl + 4 * tid);
      __syncthreads();  // outl consumed before next step re-writes red
      rec0 = (float)rv[0] * invS;
      rec1 = (float)rv[1] * invS;
      rec2 = (float)rv[2] * invS;
      rec3 = (float)rv[3] * invS;
    }

    // epilogue: matches reference op order  mem = 0.9*mem*(1-spk) + cur + rec
    float im = imem[t * 64 + be];
    mem0 = 0.9f * mem0 * (1.0f - sp0) + im * wr0 + rec0;
    mem1 = 0.9f * mem1 * (1.0f - sp1) + im * wr1 + rec1;
    mem2 = 0.9f * mem2 * (1.0f - sp2) + im * wr2 + rec2;
    mem3 = 0.9f * mem3 * (1.0f - sp3) + im * wr3 + rec3;
    int s0i = mem0 > 1.0f, s1i = mem1 > 1.0f, s2i = mem2 > 1.0f, s3i = mem3 > 1.0f;
    sp0 = (float)s0i; sp1 = (float)s1i; sp2 = (float)s2i; sp3 = (float)s3i;
    cnt += s0i + s1i + s2i + s3i;

    size_t sb = 1ull + (size_t)t * 131072ull + (size_t)be * 2048ull + (size_t)(p * 32 + nl0);
    __builtin_nontemporal_store(sp0, out + sb + 0);
    __builtin_nontemporal_store(sp1, out + sb + 1);
    __builtin_nontemporal_store(sp2, out + sb + 2);
    __builtin_nontemporal_store(sp3, out + sb + 3);
    __builtin_nontemporal_store(mem0, out + sb + 65536000ull + 0);
    __builtin_nontemporal_store(mem1, out + sb + 65536000ull + 1);
    __builtin_nontemporal_store(mem2, out + sb + 65536000ull + 2);
    __builtin_nontemporal_store(mem3, out + sb + 65536000ull + 3);

    // publish this block's 32 spike bits per batch as a tagged qword
    unsigned nib = (unsigned)(s0i | (s1i << 1) | (s2i << 2) | (s3i << 3));
    unsigned v = nib << ((tid & 7) * 4);
    v |= (unsigned)__shfl_xor((int)v, 1);
    v |= (unsigned)__shfl_xor((int)v, 2);
    v |= (unsigned)__shfl_xor((int)v, 4);
    if ((tid & 7) == 0) {
      unsigned long long qv =
          (unsigned long long)v | ((unsigned long long)(unsigned)(t + 1) << 32);
      __hip_atomic_store(&bits[(size_t)(t & 1) * 4096 + (size_t)p * 64 + be], qv,
                         __ATOMIC_RELAXED, __HIP_MEMORY_SCOPE_AGENT);
    }
  }

  // firing-rate count: one global atomic per block
  __syncthreads();
  int* csh = (int*)smem_raw;
  if (tid == 0) csh[0] = 0;
  __syncthreads();
  atomicAdd(csh, cnt);
  __syncthreads();
  if (tid == 0) atomicAdd(cnt_g, (unsigned)csh[0]);
}

__global__ void sr_fin(const unsigned* __restrict__ cnt, float* __restrict__ out) {
  out[0] = (float)((double)(*cnt) / 65536000.0);
}

extern "C" void kernel_launch(void* const* d_in, const int* in_sizes, int n_in,
                              void* d_out, int out_size, void* d_ws, size_t ws_size,
                              hipStream_t stream) {
  const float* x     = (const float*)d_in[0];  // (64,500,1)
  const float* w_in  = (const float*)d_in[1];  // (1,1)
  const float* w_res = (const float*)d_in[2];  // (2048,1)
  const float* W     = (const float*)d_in[3];  // (2048,2048)
  float* out = (float*)d_out;
  char* ws = (char*)d_ws;

  unsigned* wmax_bits = (unsigned*)(ws + WMAX_OFF);
  unsigned* cntp      = (unsigned*)(ws + CNT_OFF);
  float* imem         = (float*)(ws + IMEM_OFF);
  unsigned long long* bits = (unsigned long long*)(ws + BITS_OFF);
  v4i* wfr            = (v4i*)(ws + WFRAG_OFF);

  sr_prep<<<1, 128, 0, stream>>>(x, w_in, imem, wmax_bits, cntp);
  sr_wmax<<<1024, 256, 0, stream>>>(W, wmax_bits);
  sr_wquant<<<2048, 256, 0, stream>>>(W, wmax_bits, wfr);
  sr_main<<<64, 512, 65536, stream>>>(imem, wfr, bits, w_res, wmax_bits, cntp, out);
  sr_fin<<<1, 1, 0, stream>>>(cntp, out);
}

// Round 2
// 2282.916 us; speedup vs baseline: 1.2134x; 1.2134x over previous
//
#include <hip/hip_runtime.h>

typedef int v4i __attribute__((ext_vector_type(4)));

// ws layout (bytes)
#define WMAX_OFF   0
#define CNT_OFF    4
#define IMEM_OFF   64        // float[500*64]
#define BITS_OFF   131072    // ull[2*8192]  self-validating {bits32, tag32} packets
#define WFRAG_OFF  262144    // v4i[8192*64] quantized i8 hi/lo W fragments (8 MB)

__global__ void sr_prep(const float* __restrict__ x, const float* __restrict__ w_in,
                        float* __restrict__ imem, unsigned* wmax_bits, unsigned* cnt) {
  int b = threadIdx.x;
  if (b == 64) *wmax_bits = 0u;
  if (b == 65) *cnt = 0u;
  if (b < 64) {
    float wi = w_in[0];
    float im = 0.0f;
    for (int t = 0; t < 500; ++t) {
      im = 0.8f * im + x[b * 500 + t] * wi;   // input LIF (Vmem mode, no reset)
      imem[t * 64 + b] = im;
    }
  }
}

__global__ void sr_wmax(const float* __restrict__ W, unsigned* wmax_bits) {
  __shared__ unsigned sm;
  if (threadIdx.x == 0) sm = 0u;
  __syncthreads();
  float m = 0.0f;
  for (size_t i = (size_t)blockIdx.x * 256 + threadIdx.x; i < 4194304ull; i += 262144ull)
    m = fmaxf(m, fabsf(W[i]));
  atomicMax(&sm, __float_as_uint(m));   // floats >=0: uint order == float order
  __syncthreads();
  if (threadIdx.x == 0) atomicMax(wmax_bits, sm);
}

// Quantize W to 16-bit fixed point (hi*256+lo i8 planes) laid out as MFMA B-fragments.
// k-slot (q, d, i) of wave-w/frag-kl  <->  neuron m = (16w + 4kl + q)*16 + 4i + d.
// Block = (p, w) pair; stages a 16x256 W tile in LDS with coalesced loads.
__global__ void sr_wquant(const float* __restrict__ W, const unsigned* __restrict__ wmax_bits,
                          v4i* __restrict__ wfr) {
  __shared__ float ws[16][257];
  const int p = blockIdx.x >> 3;     // 0..127 (16-neuron slice)
  const int w = blockIdx.x & 7;      // wave / K-slice [256w, 256w+256)
  const int tid = threadIdx.x;       // 512
  {
    int r = tid >> 5;                // 16 rows
    int c0 = (tid & 31) * 8;         // 8 floats each, coalesced
    const float* src = W + (size_t)(p * 16 + r) * 2048 + 256 * w + c0;
    #pragma unroll
    for (int j = 0; j < 8; ++j) ws[r][c0 + j] = src[j];
  }
  __syncthreads();
  const int fl = tid >> 6;           // 0..7 : kl = fl>>1, sp = fl&1
  const int kl = fl >> 1, sp = fl & 1;
  const int lane = tid & 63;
  const int col = lane & 15;         // output neuron (local)
  const int q = lane >> 4;
  const float S = 32000.0f / __uint_as_float(*wmax_bits);
  int dw[4] = {0, 0, 0, 0};
  #pragma unroll
  for (int j = 0; j < 16; ++j) {
    int d = j >> 2, i = j & 3;
    float wv = ws[col][(4 * kl + q) * 16 + 4 * i + d];
    int qv = (int)rintf(wv * S);     // |qv| <= 32000
    int hi = (qv + 128) >> 8;        // i8 range
    int lo = qv - (hi << 8);         // i8 range; hi*256+lo == qv exactly
    int v = sp ? lo : hi;
    dw[d] |= (v & 255) << (8 * i);
  }
  v4i o; o[0] = dw[0]; o[1] = dw[1]; o[2] = dw[2]; o[3] = dw[3];
  wfr[(size_t)((((p * 8 + w) * 4 + kl) * 2 + sp)) * 64 + lane] = o;
}

// Persistent dataflow kernel: 128 blocks (16 neurons each) x 512 threads (8 waves).
// Per step: coalesced tag-checked poll of all 8192 spike packets (16/thread, batched
// loads), LDS spike table (XOR-swizzled), 32 i8 MFMAs/wave, exact int32 LDS K-reduce,
// fp32 epilogue, publish-before-records.
__global__ __launch_bounds__(512, 2)
void sr_main(const float* __restrict__ imem, const v4i* __restrict__ wfr,
             unsigned long long* bits, const float* __restrict__ w_res,
             const unsigned* __restrict__ wmax_bits, unsigned* cnt_g,
             float* __restrict__ out) {
  extern __shared__ char smem_raw[];
  unsigned* spk_lds = (unsigned*)smem_raw;        // [8192] u32 = 32KB  (phase A)
  v4i* redv = (v4i*)smem_raw;                     // [32][64] v4i = 32KB (phase B, aliased)
  int* outl = (int*)(smem_raw + 32768);           // [1024] int = 4KB   (disjoint)

  const int p = blockIdx.x;          // 0..127
  const int tid = threadIdx.x;
  const int w = tid >> 6;            // wave = K-slice [256w, 256w+256)
  const int lane = tid & 63;
  const int q = lane >> 4;
  const int col = lane & 15;

  // resident W fragments: 8 x v4i = 32 VGPRs
  v4i wf[4][2];
  #pragma unroll
  for (int kl = 0; kl < 4; ++kl)
    #pragma unroll
    for (int sp = 0; sp < 2; ++sp)
      wf[kl][sp] = wfr[(size_t)((((p * 8 + w) * 4 + kl) * 2 + sp)) * 64 + lane];

  // epilogue ownership: thread -> batch be, neurons {16p + nl, +1}
  const int be = tid >> 3;
  const int h = tid & 7;
  const int nl = h * 2;
  const float wr0 = w_res[p * 16 + nl + 0];
  const float wr1 = w_res[p * 16 + nl + 1];
  float mem0 = 0, mem1 = 0, sp0 = 0, sp1 = 0;
  int cnt = 0;
  const float invS = __uint_as_float(*wmax_bits) / 32000.0f;
  const v4i vzero = {0, 0, 0, 0};
  const int pubshift = (h >> 1) * 8 + 2 * (h & 1);  // neuron n -> bit 8*(n>>2)+(n&3)

  for (int t = 0; t < 500; ++t) {
    float im = imem[t * 64 + be];    // independent load, overlaps poll
    float rec0 = 0, rec1 = 0;
    if (t > 0) {
      const unsigned long long* src = bits + (size_t)((t - 1) & 1) * 8192 + tid;
      unsigned long long qw[16];
      bool ok = false;
      int guard = 0;
      do {  // 16 coalesced batched loads (thread tid owns packets tid+512j)
        #pragma unroll
        for (int j = 0; j < 16; ++j)
          qw[j] = __hip_atomic_load(src + 512 * j, __ATOMIC_RELAXED, __HIP_MEMORY_SCOPE_AGENT);
        unsigned bad = 0;
        #pragma unroll
        for (int j = 0; j < 16; ++j) bad |= (unsigned)(qw[j] >> 32) ^ (unsigned)t;
        ok = (bad == 0);
        if (!ok) __builtin_amdgcn_s_sleep(1);
      } while (!ok && ++guard < (1 << 20));

      // copy spike words to LDS with XOR swizzle: idx = (P&~63)|((P&63)^((P>>6&3)<<4))
      #pragma unroll
      for (int j = 0; j < 16; ++j) {
        int P = tid + 512 * j;
        int idx = (P & ~63) | ((P & 63) ^ (((P >> 6) & 3) << 4));
        spk_lds[idx] = (unsigned)qw[j];
      }
      __syncthreads();  // B1: spike table ready

      // per-lane A words: 16 ds_read_b32, 2-way banks max
      unsigned ww[16];
      #pragma unroll
      for (int f = 0; f < 16; ++f) {
        int kl = f & 3, bt = f >> 2;
        ww[f] = spk_lds[(16 * w + 4 * kl + q) * 64 + ((bt * 16 + col) ^ (q << 4))];
      }
      __syncthreads();  // B2: spk_lds consumed; redv may clobber

      v4i acc[4][2];
      #pragma unroll
      for (int bt = 0; bt < 4; ++bt) { acc[bt][0] = vzero; acc[bt][1] = vzero; }
      #pragma unroll
      for (int f = 0; f < 16; ++f) {
        int kl = f & 3, bt = f >> 2;
        unsigned wb = ww[f];
        v4i a;  // bits -> i8 {0,1}: byte i of a[d] = bit (8i+d) = neuron (4i+d)
        a[0] = (int)((wb >> 0) & 0x01010101u);
        a[1] = (int)((wb >> 1) & 0x01010101u);
        a[2] = (int)((wb >> 2) & 0x01010101u);
        a[3] = (int)((wb >> 3) & 0x01010101u);
        acc[bt][0] = __builtin_amdgcn_mfma_i32_16x16x64_i8(a, wf[kl][0], acc[bt][0], 0, 0, 0);
        acc[bt][1] = __builtin_amdgcn_mfma_i32_16x16x64_i8(a, wf[kl][1], acc[bt][1], 0, 0, 0);
      }
      // combine planes exactly; write K-partials
      #pragma unroll
      for (int bt = 0; bt < 4; ++bt) {
        v4i c = acc[bt][0] * 256 + acc[bt][1];
        redv[(w * 4 + bt) * 64 + lane] = c;   // contiguous b128
      }
      __syncthreads();  // B3
      if (w < 4) {      // wave v reduces tile bt=v over 8 K-slices
        v4i s = vzero;
        #pragma unroll
        for (int ww2 = 0; ww2 < 8; ++ww2) s += redv[(ww2 * 4 + w) * 64 + lane];
        // C/D layout: col=lane&15 (neuron), row=(lane>>4)*4+reg (batch)
        int ob = (w * 16 + (lane >> 4) * 4) * 16 + (lane & 15);
        outl[ob]      = s[0];
        outl[ob + 16] = s[1];
        outl[ob + 32] = s[2];
        outl[ob + 48] = s[3];
      }
      __syncthreads();  // B4: outl ready; redv fully consumed
      int2 rv = *(const int2*)(outl + be * 16 + nl);
      rec0 = (float)rv.x * invS;
      rec1 = (float)rv.y * invS;
    }

    // epilogue, reference op order: mem = 0.9*mem*(1-spk) + cur + rec
    mem0 = 0.9f * mem0 * (1.0f - sp0) + im * wr0 + rec0;
    mem1 = 0.9f * mem1 * (1.0f - sp1) + im * wr1 + rec1;
    int s0i = mem0 > 1.0f, s1i = mem1 > 1.0f;
    sp0 = (float)s0i; sp1 = (float)s1i;

    // publish FIRST (critical path), records after
    unsigned v = ((unsigned)(s0i | (s1i << 1))) << pubshift;
    v |= (unsigned)__shfl_xor((int)v, 1);
    v |= (unsigned)__shfl_xor((int)v, 2);
    v |= (unsigned)__shfl_xor((int)v, 4);
    if (h == 0) {
      unsigned long long qv =
          (unsigned long long)v | ((unsigned long long)(unsigned)(t + 1) << 32);
      __hip_atomic_store(&bits[(size_t)(t & 1) * 8192 + (size_t)p * 64 + be], qv,
                         __ATOMIC_RELAXED, __HIP_MEMORY_SCOPE_AGENT);
    }
    cnt += s0i + s1i;

    size_t sb = 1ull + (size_t)t * 131072ull + (size_t)be * 2048ull + (size_t)(p * 16 + nl);
    __builtin_nontemporal_store(sp0, out + sb + 0);
    __builtin_nontemporal_store(sp1, out + sb + 1);
    __builtin_nontemporal_store(mem0, out + sb + 65536000ull + 0);
    __builtin_nontemporal_store(mem1, out + sb + 65536000ull + 1);
  }

  // firing-rate count: one global atomic per block
  __syncthreads();
  int* csh = (int*)smem_raw;
  if (tid == 0) csh[0] = 0;
  __syncthreads();
  atomicAdd(csh, cnt);
  __syncthreads();
  if (tid == 0) atomicAdd(cnt_g, (unsigned)csh[0]);
}

__global__ void sr_fin(const unsigned* __restrict__ cnt, float* __restrict__ out) {
  out[0] = (float)((double)(*cnt) / 65536000.0);
}

extern "C" void kernel_launch(void* const* d_in, const int* in_sizes, int n_in,
                              void* d_out, int out_size, void* d_ws, size_t ws_size,
                              hipStream_t stream) {
  const float* x     = (const float*)d_in[0];  // (64,500,1)
  const float* w_in  = (const float*)d_in[1];  // (1,1)
  const float* w_res = (const float*)d_in[2];  // (2048,1)
  const float* W     = (const float*)d_in[3];  // (2048,2048)
  float* out = (float*)d_out;
  char* ws = (char*)d_ws;

  unsigned* wmax_bits = (unsigned*)(ws + WMAX_OFF);
  unsigned* cntp      = (unsigned*)(ws + CNT_OFF);
  float* imem         = (float*)(ws + IMEM_OFF);
  unsigned long long* bits = (unsigned long long*)(ws + BITS_OFF);
  v4i* wfr            = (v4i*)(ws + WFRAG_OFF);

  sr_prep<<<1, 128, 0, stream>>>(x, w_in, imem, wmax_bits, cntp);
  sr_wmax<<<1024, 256, 0, stream>>>(W, wmax_bits);
  sr_wquant<<<1024, 512, 0, stream>>>(W, wmax_bits, wfr);
  sr_main<<<128, 512, 36864, stream>>>(imem, wfr, bits, w_res, wmax_bits, cntp, out);
  sr_fin<<<1, 1, 0, stream>>>(cntp, out);
}